// Round 6
// baseline (5002.060 us; speedup 1.0000x reference)
//
#include <hip/hip_runtime.h>
#include <math.h>

// Problem dims (fixed)
#define NOTES 78
#define IN_DIM 80
#define T_HID 64
#define N_HID 2
#define BATCH 64
#define TLEN 128
#define NSEQ (BATCH * NOTES)          // 4992 time-LSTM sequences
#define NBT  (BATCH * TLEN)           // 8192 note-LSTM sequences
#define NROWS (NSEQ * TLEN)           // 638976 (seq,t) rows

#define GXN_BYTES ((size_t)NOTES * NBT * 8 * 4)            // 20,447,232 (fallback only)
#define GX_BYTES  ((size_t)NROWS * 256 * 4)                // 654,311,424

__device__ __forceinline__ float sigf(float x) { return 1.0f / (1.0f + expf(-x)); }
__device__ __forceinline__ float rdl(float v, int k) {
    return __int_as_float(__builtin_amdgcn_readlane(__float_as_int(v), k));
}

// ---------------------------------------------------------------------------
// Kernel 1: gx GEMM (R8 version, measured ~550us; known codegen).
// Tile 128 rows x 128 gates, K=80 staged transposed in LDS (80 KB, 2 blk/CU).
// ---------------------------------------------------------------------------
#define GM 128
#define GN 128
__global__ __launch_bounds__(256, 2)
void gx_gemm(const float* __restrict__ x,      // [NROWS][80]
             const float* __restrict__ w_ih,   // [256][80]
             const float* __restrict__ b_ih,
             const float* __restrict__ b_hh,
             float* __restrict__ gx) {         // [NROWS][256]
    __shared__ float xT[IN_DIM][GM];   // 40 KB, xT[k][r]
    __shared__ float wT[IN_DIM][GN];   // 40 KB, wT[k][g]

    const int tid = threadIdx.x;
    const size_t row0 = (size_t)blockIdx.x * GM;
    const int gbase = blockIdx.y * GN;

    {
        const int r = tid >> 1;
        const int kh = (tid & 1) * 40;
        const float4* src = (const float4*)(x + (row0 + r) * IN_DIM + kh);
        const float4* ws  = (const float4*)(w_ih + (size_t)(gbase + r) * IN_DIM + kh);
#pragma unroll
        for (int j = 0; j < 10; j++) {
            const float4 v = src[j];
            const int k = kh + 4 * j;
            xT[k + 0][r] = v.x; xT[k + 1][r] = v.y;
            xT[k + 2][r] = v.z; xT[k + 3][r] = v.w;
        }
#pragma unroll
        for (int j = 0; j < 10; j++) {
            const float4 v = ws[j];
            const int k = kh + 4 * j;
            wT[k + 0][r] = v.x; wT[k + 1][r] = v.y;
            wT[k + 2][r] = v.z; wT[k + 3][r] = v.w;
        }
    }
    __syncthreads();

    const int gg = (tid & 15) << 3;    // 8 gates
    const int rg = (tid >> 4) << 3;    // 8 rows
    float acc[8][8];
#pragma unroll
    for (int i = 0; i < 8; i++)
#pragma unroll
        for (int j = 0; j < 8; j++) acc[i][j] = 0.0f;

#pragma unroll 4
    for (int k = 0; k < IN_DIM; k++) {
        float a[8], b[8];
        *(float4*)&a[0] = *(const float4*)&xT[k][rg];
        *(float4*)&a[4] = *(const float4*)&xT[k][rg + 4];
        *(float4*)&b[0] = *(const float4*)&wT[k][gg];
        *(float4*)&b[4] = *(const float4*)&wT[k][gg + 4];
#pragma unroll
        for (int i = 0; i < 8; i++)
#pragma unroll
            for (int j = 0; j < 8; j++)
                acc[i][j] = fmaf(a[i], b[j], acc[i][j]);
    }

    float bias[8];
#pragma unroll
    for (int j = 0; j < 8; j++)
        bias[j] = b_ih[gbase + gg + j] + b_hh[gbase + gg + j];

#pragma unroll
    for (int i = 0; i < 8; i++) {
        float* orow = gx + (row0 + rg + i) * 256 + gbase + gg;
        *(float4*)&orow[0] = make_float4(acc[i][0] + bias[0], acc[i][1] + bias[1],
                                         acc[i][2] + bias[2], acc[i][3] + bias[3]);
        *(float4*)&orow[4] = make_float4(acc[i][4] + bias[4], acc[i][5] + bias[5],
                                         acc[i][6] + bias[6], acc[i][7] + bias[7]);
    }
}

// ---------------------------------------------------------------------------
// Kernel 2: h-recurrence v3.
// R9 post-mortem: 1 wave/SIMD exposed all latency (85% stall). Fix:
//   - 512-thr blocks (8 waves => 2 waves/SIMD inside one block), SPW=4
//     => 32 seqs/block, grid = 156 exactly (no masking).
//   - q prefetched one step ahead into registers (HBM latency hidden).
//   - NO gxn projection here (was 55 ds_bpermute/wave-step): h_t is stored
//     into gx[seq][t][0:64] (the i-gate slot, already consumed: the q(t)
//     load completes before h(t) exists => store ordered after load).
// Per-block: LDS pipe 8w*128*64*12cy = 328us, VALU ~312us -> balanced.
// ---------------------------------------------------------------------------
#define SPW 4
__global__ __launch_bounds__(512, 2)
void rec_h3(float* __restrict__ gx,            // [NSEQ][TLEN][256] (h into col 0..63)
            const float* __restrict__ w_hh) {  // [256][64]
    __shared__ float4 wT4[16][256];    // 64 KB: wT4[k4][g] = w_hh[g][4k4..+3]

    const int tid = threadIdx.x;
    const int lane = tid & 63;
    const int w = tid >> 6;
    const int sb = blockIdx.x * (8 * SPW) + w * SPW;

    if (tid < 256) {
#pragma unroll
        for (int j = 0; j < 16; j++)
            wT4[j][tid] = *(const float4*)(w_hh + (size_t)tid * T_HID + 4 * j);
    }
    __syncthreads();

    float* gp[SPW];
#pragma unroll
    for (int s = 0; s < SPW; s++)
        gp[s] = gx + (size_t)(sb + s) * TLEN * 256 + lane;

    float h[SPW], c[SPW], q0[SPW], q1[SPW], q2[SPW], q3[SPW];
#pragma unroll
    for (int s = 0; s < SPW; s++) {
        h[s] = 0.0f; c[s] = 0.0f;
        q0[s] = gp[s][0];  q1[s] = gp[s][64];
        q2[s] = gp[s][128]; q3[s] = gp[s][192];
    }

    for (int t = 0; t < TLEN; t++) {
        // prefetch q(t+1) (uniform branch; latency hides under MAC loop)
        float n0[SPW], n1[SPW], n2[SPW], n3[SPW];
        const bool pf = (t + 1 < TLEN);
        if (pf) {
#pragma unroll
            for (int s = 0; s < SPW; s++) {
                n0[s] = gp[s][256]; n1[s] = gp[s][320];
                n2[s] = gp[s][384]; n3[s] = gp[s][448];
            }
        }

        float a0[SPW], a1[SPW], a2[SPW], a3[SPW];
#pragma unroll
        for (int s = 0; s < SPW; s++) { a0[s]=0.f; a1[s]=0.f; a2[s]=0.f; a3[s]=0.f; }

#pragma unroll
        for (int k4 = 0; k4 < 16; k4++) {
            const float4 w0 = wT4[k4][lane];          // shared across SPW seqs
            const float4 w1 = wT4[k4][64 + lane];
            const float4 w2 = wT4[k4][128 + lane];
            const float4 w3 = wT4[k4][192 + lane];
#pragma unroll
            for (int s = 0; s < SPW; s++) {
                const float r0 = rdl(h[s], 4 * k4 + 0);
                const float r1 = rdl(h[s], 4 * k4 + 1);
                const float r2 = rdl(h[s], 4 * k4 + 2);
                const float r3 = rdl(h[s], 4 * k4 + 3);
                a0[s] = fmaf(w0.x, r0, a0[s]); a0[s] = fmaf(w0.y, r1, a0[s]);
                a0[s] = fmaf(w0.z, r2, a0[s]); a0[s] = fmaf(w0.w, r3, a0[s]);
                a1[s] = fmaf(w1.x, r0, a1[s]); a1[s] = fmaf(w1.y, r1, a1[s]);
                a1[s] = fmaf(w1.z, r2, a1[s]); a1[s] = fmaf(w1.w, r3, a1[s]);
                a2[s] = fmaf(w2.x, r0, a2[s]); a2[s] = fmaf(w2.y, r1, a2[s]);
                a2[s] = fmaf(w2.z, r2, a2[s]); a2[s] = fmaf(w2.w, r3, a2[s]);
                a3[s] = fmaf(w3.x, r0, a3[s]); a3[s] = fmaf(w3.y, r1, a3[s]);
                a3[s] = fmaf(w3.z, r2, a3[s]); a3[s] = fmaf(w3.w, r3, a3[s]);
            }
        }

#pragma unroll
        for (int s = 0; s < SPW; s++) {
            const float ip = q0[s] + a0[s];
            const float fp = q1[s] + a1[s];
            const float gg = q2[s] + a2[s];
            const float op = q3[s] + a3[s];
            c[s] = sigf(fp) * c[s] + sigf(ip) * tanhf(gg);
            h[s] = sigf(op) * tanhf(c[s]);
            gp[s][0] = h[s];            // store h_t into consumed i-gate slot
            gp[s] += 256;
        }
        if (pf) {
#pragma unroll
            for (int s = 0; s < SPW; s++) {
                q0[s] = n0[s]; q1[s] = n1[s]; q2[s] = n2[s]; q3[s] = n3[s];
            }
        }
    }
}

// ---------------------------------------------------------------------------
// Kernel 3: fused note-input projection + note-LSTM scan.
// Thread = bt; per note n: load h-row (64 f), project to 8 gates with
// LDS-broadcast weights, run the 2-unit LSTM cell, threshold.
// ---------------------------------------------------------------------------
__global__ __launch_bounds__(64)
void note_scan2(const float* __restrict__ gx,      // h in [seq][t][0:64]
                const float* __restrict__ w_ih_n,  // [8][64]
                const float* __restrict__ w_hh_n,  // [8][2]
                const float* __restrict__ b_ih_n,
                const float* __restrict__ b_hh_n,
                float* __restrict__ out) {
    __shared__ float4 wn4[16][8];      // 2 KB: wn4[k4][nj] = w_ih_n[nj][4k4..+3]

    const int tid = threadIdx.x;
    const int bt = blockIdx.x * 64 + tid;          // < 8192
    const int b = bt >> 7, t = bt & 127;

    for (int j = tid; j < 128; j += 64)
        wn4[j >> 3][j & 7] = *(const float4*)(w_ih_n + (j & 7) * T_HID + (j >> 3) * 4);

    float wh[16], bias[8];
#pragma unroll
    for (int i = 0; i < 16; i++) wh[i] = w_hh_n[i];
#pragma unroll
    for (int nj = 0; nj < 8; nj++) bias[nj] = b_ih_n[nj] + b_hh_n[nj];
    __syncthreads();

    float h0 = 0.f, h1 = 0.f, c0 = 0.f, c1 = 0.f;
    const float* hrow = gx + ((size_t)(b * NOTES) * TLEN + t) * 256;
    float4* op = (float4*)(out + (size_t)bt * (NOTES * N_HID));

    for (int n0i = 0; n0i < NOTES; n0i += 2) {
        float r[4];
#pragma unroll
        for (int u = 0; u < 2; u++) {
            float4 hv[16];
#pragma unroll
            for (int j = 0; j < 16; j++) hv[j] = *(const float4*)(hrow + 4 * j);
            float p[8];
#pragma unroll
            for (int nj = 0; nj < 8; nj++) p[nj] = bias[nj];
#pragma unroll
            for (int k4 = 0; k4 < 16; k4++) {
                const float4 hh = hv[k4];
#pragma unroll
                for (int nj = 0; nj < 8; nj++) {
                    const float4 ww = wn4[k4][nj];  // broadcast read
                    p[nj] = fmaf(ww.x, hh.x, p[nj]);
                    p[nj] = fmaf(ww.y, hh.y, p[nj]);
                    p[nj] = fmaf(ww.z, hh.z, p[nj]);
                    p[nj] = fmaf(ww.w, hh.w, p[nj]);
                }
            }
            const float i0 = p[0] + wh[0]  * h0 + wh[1]  * h1;
            const float i1 = p[1] + wh[2]  * h0 + wh[3]  * h1;
            const float f0 = p[2] + wh[4]  * h0 + wh[5]  * h1;
            const float f1 = p[3] + wh[6]  * h0 + wh[7]  * h1;
            const float g0 = p[4] + wh[8]  * h0 + wh[9]  * h1;
            const float g1 = p[5] + wh[10] * h0 + wh[11] * h1;
            const float o0 = p[6] + wh[12] * h0 + wh[13] * h1;
            const float o1 = p[7] + wh[14] * h0 + wh[15] * h1;
            c0 = sigf(f0) * c0 + sigf(i0) * tanhf(g0);
            c1 = sigf(f1) * c1 + sigf(i1) * tanhf(g1);
            h0 = sigf(o0) * tanhf(c0);
            h1 = sigf(o1) * tanhf(c1);
            r[2 * u + 0] = (h0 > 0.5f) ? 1.0f : 0.0f;
            r[2 * u + 1] = (h1 > 0.5f) ? 1.0f : 0.0f;
            hrow += TLEN * 256;        // next note
        }
        op[n0i >> 1] = make_float4(r[0], r[1], r[2], r[3]);
    }
}

// ---------------------------------------------------------------------------
// Fallback (small workspace): R5 fused kernel (measured 1160us) + old scan.
// ---------------------------------------------------------------------------
#define SB 4
__global__ __launch_bounds__(512, 4)
void time_lstm_fused_fb(const float* __restrict__ x,
                        const float* __restrict__ w_ih,
                        const float* __restrict__ w_hh,
                        const float* __restrict__ b_ih,
                        const float* __restrict__ b_hh,
                        const float* __restrict__ w_ih_n,
                        const float* __restrict__ b_ih_n,
                        const float* __restrict__ b_hh_n,
                        float* __restrict__ gxn) {
    __shared__ float hbuf[SB][T_HID];
    __shared__ float Gx[2][SB][256];
    __shared__ float Gh[2][SB][256];

    const int tid  = threadIdx.x;
    const int s0   = blockIdx.x * SB;
    const int wid  = tid >> 6;
    const int lane = tid & 63;
    const bool isx = (wid < 4);
    const int lw   = isx ? wid : (wid - 4);
    const int kh   = lw >> 1;
    const int gh   = lw & 1;
    const int g0   = (gh << 7) | (2 * lane);

    float4 wA[10], wB[10];
    float biasA = 0.0f, biasB = 0.0f;
    if (isx) {
        const float4* pA = (const float4*)(w_ih + (size_t)g0 * IN_DIM + 40 * kh);
        const float4* pB = (const float4*)(w_ih + (size_t)(g0 + 1) * IN_DIM + 40 * kh);
#pragma unroll
        for (int j = 0; j < 10; j++) { wA[j] = pA[j]; wB[j] = pB[j]; }
        if (kh == 0) {
            biasA = b_ih[g0] + b_hh[g0];
            biasB = b_ih[g0 + 1] + b_hh[g0 + 1];
        }
    } else {
        const float4* pA = (const float4*)(w_hh + (size_t)g0 * T_HID + 32 * kh);
        const float4* pB = (const float4*)(w_hh + (size_t)(g0 + 1) * T_HID + 32 * kh);
#pragma unroll
        for (int j = 0; j < 8; j++) { wA[j] = pA[j]; wB[j] = pB[j]; }
    }

    const float* xr[SB];
#pragma unroll
    for (int s = 0; s < SB; s++) xr[s] = x + (size_t)(s0 + s) * TLEN * IN_DIM;

    const int ol = 40 * kh + (lane < 39 ? lane : 39);

    float xa[SB], xna[SB];
    if (isx) {
#pragma unroll
        for (int s = 0; s < SB; s++) xa[s] = xr[s][ol];
    }

    float cst = 0.0f;
    const int hol = (kh << 5) | (lane & 31);
    const int nj = (lane >> 3) & 7;
    const int nk = lane & 7;
    float wn[8];
    float nbias = 0.0f;
    float* gout = gxn;
    if (!isx) {
#pragma unroll
        for (int i = 0; i < 8; i++) wn[i] = w_ih_n[nj * 64 + nk * 8 + i];
        nbias = b_ih_n[nj] + b_hh_n[nj];
        const int sglb = s0 + lw;
        const int nb = sglb / NOTES, nn = sglb % NOTES;
        gout = gxn + ((size_t)nn * NBT + (size_t)nb * TLEN) * 8 + nj;
    }

    if (tid < SB * T_HID) hbuf[tid >> 6][tid & 63] = 0.0f;
    __syncthreads();

    for (int t = 0; t < TLEN; t++) {
        if (isx) {
            if (t + 1 < TLEN) {
#pragma unroll
                for (int s = 0; s < SB; s++) xna[s] = xr[s][(t + 1) * IN_DIM + ol];
            }
            float aA[SB], aB[SB];
#pragma unroll
            for (int s = 0; s < SB; s++) { aA[s] = biasA; aB[s] = biasB; }
#pragma unroll
            for (int k4 = 0; k4 < 10; k4++) {
                const float4 vA = wA[k4], vB = wB[k4];
#pragma unroll
                for (int s = 0; s < SB; s++) {
                    const float r0 = rdl(xa[s], 4 * k4 + 0);
                    const float r1 = rdl(xa[s], 4 * k4 + 1);
                    const float r2 = rdl(xa[s], 4 * k4 + 2);
                    const float r3 = rdl(xa[s], 4 * k4 + 3);
                    aA[s] = fmaf(vA.x, r0, aA[s]);  aB[s] = fmaf(vB.x, r0, aB[s]);
                    aA[s] = fmaf(vA.y, r1, aA[s]);  aB[s] = fmaf(vB.y, r1, aB[s]);
                    aA[s] = fmaf(vA.z, r2, aA[s]);  aB[s] = fmaf(vB.z, r2, aB[s]);
                    aA[s] = fmaf(vA.w, r3, aA[s]);  aB[s] = fmaf(vB.w, r3, aB[s]);
                }
            }
#pragma unroll
            for (int s = 0; s < SB; s++)
                *(float2*)&Gx[kh][s][g0] = make_float2(aA[s], aB[s]);
        } else {
            if (t > 0) {
                float p = 0.0f;
#pragma unroll
                for (int i = 0; i < 8; i++) p = fmaf(wn[i], hbuf[lw][nk * 8 + i], p);
                p += __shfl_xor(p, 1);
                p += __shfl_xor(p, 2);
                p += __shfl_xor(p, 4);
                if (nk == 0) gout[(size_t)(t - 1) * 8] = p + nbias;
            }
            float hv[SB];
#pragma unroll
            for (int s = 0; s < SB; s++) hv[s] = hbuf[s][hol];
            float aA[SB], aB[SB];
#pragma unroll
            for (int s = 0; s < SB; s++) { aA[s] = 0.0f; aB[s] = 0.0f; }
#pragma unroll
            for (int k4 = 0; k4 < 8; k4++) {
                const float4 vA = wA[k4], vB = wB[k4];
#pragma unroll
                for (int s = 0; s < SB; s++) {
                    const float r0 = rdl(hv[s], 4 * k4 + 0);
                    const float r1 = rdl(hv[s], 4 * k4 + 1);
                    const float r2 = rdl(hv[s], 4 * k4 + 2);
                    const float r3 = rdl(hv[s], 4 * k4 + 3);
                    aA[s] = fmaf(vA.x, r0, aA[s]);  aB[s] = fmaf(vB.x, r0, aB[s]);
                    aA[s] = fmaf(vA.y, r1, aA[s]);  aB[s] = fmaf(vB.y, r1, aB[s]);
                    aA[s] = fmaf(vA.z, r2, aA[s]);  aB[s] = fmaf(vB.z, r2, aB[s]);
                    aA[s] = fmaf(vA.w, r3, aA[s]);  aB[s] = fmaf(vB.w, r3, aB[s]);
                }
            }
#pragma unroll
            for (int s = 0; s < SB; s++)
                *(float2*)&Gh[kh][s][g0] = make_float2(aA[s], aB[s]);
        }
        __syncthreads();

        if (!isx) {
            const float i_p = Gx[0][lw][lane]       + Gx[1][lw][lane]
                            + Gh[0][lw][lane]       + Gh[1][lw][lane];
            const float f_p = Gx[0][lw][64 + lane]  + Gx[1][lw][64 + lane]
                            + Gh[0][lw][64 + lane]  + Gh[1][lw][64 + lane];
            const float g_p = Gx[0][lw][128 + lane] + Gx[1][lw][128 + lane]
                            + Gh[0][lw][128 + lane] + Gh[1][lw][128 + lane];
            const float o_p = Gx[0][lw][192 + lane] + Gx[1][lw][192 + lane]
                            + Gh[0][lw][192 + lane] + Gh[1][lw][192 + lane];
            cst = sigf(f_p) * cst + sigf(i_p) * tanhf(g_p);
            const float h = sigf(o_p) * tanhf(cst);
            hbuf[lw][lane] = h;
        } else if (t + 1 < TLEN) {
#pragma unroll
            for (int s = 0; s < SB; s++) xa[s] = xna[s];
        }
        __syncthreads();
    }

    if (!isx) {
        float p = 0.0f;
#pragma unroll
        for (int i = 0; i < 8; i++) p = fmaf(wn[i], hbuf[lw][nk * 8 + i], p);
        p += __shfl_xor(p, 1);
        p += __shfl_xor(p, 2);
        p += __shfl_xor(p, 4);
        if (nk == 0) gout[(size_t)(TLEN - 1) * 8] = p + nbias;
    }
}

__global__ __launch_bounds__(64)
void note_scan_kernel(const float* __restrict__ gxn,
                      const float* __restrict__ w_hh_n,
                      float* __restrict__ out) {
    const int bt = blockIdx.x * 64 + threadIdx.x;
    float wh[16];
#pragma unroll
    for (int i = 0; i < 16; i++) wh[i] = w_hh_n[i];
    float h0 = 0.f, h1 = 0.f, c0 = 0.f, c1 = 0.f;

    const float4* gp = (const float4*)gxn;
    float4* op = (float4*)(out + (size_t)bt * (NOTES * N_HID));

    size_t idx = (size_t)bt * 2;
    float4 ga = gp[idx], gb = gp[idx + 1];
    for (int n0i = 0; n0i < NOTES; n0i += 2) {
        float r[4];
#pragma unroll
        for (int u = 0; u < 2; u++) {
            const int n = n0i + u;
            float4 na, nb2;
            if (n + 1 < NOTES) {
                const size_t nidx = ((size_t)(n + 1) * NBT + bt) * 2;
                na  = gp[nidx];
                nb2 = gp[nidx + 1];
            }
            const float i0 = ga.x + wh[0]  * h0 + wh[1]  * h1;
            const float i1 = ga.y + wh[2]  * h0 + wh[3]  * h1;
            const float f0 = ga.z + wh[4]  * h0 + wh[5]  * h1;
            const float f1 = ga.w + wh[6]  * h0 + wh[7]  * h1;
            const float g0 = gb.x + wh[8]  * h0 + wh[9]  * h1;
            const float g1 = gb.y + wh[10] * h0 + wh[11] * h1;
            const float o0 = gb.z + wh[12] * h0 + wh[13] * h1;
            const float o1 = gb.w + wh[14] * h0 + wh[15] * h1;
            c0 = sigf(f0) * c0 + sigf(i0) * tanhf(g0);
            c1 = sigf(f1) * c1 + sigf(i1) * tanhf(g1);
            h0 = sigf(o0) * tanhf(c0);
            h1 = sigf(o1) * tanhf(c1);
            r[2 * u + 0] = (h0 > 0.5f) ? 1.0f : 0.0f;
            r[2 * u + 1] = (h1 > 0.5f) ? 1.0f : 0.0f;
            ga = na; gb = nb2;
        }
        op[n0i >> 1] = make_float4(r[0], r[1], r[2], r[3]);
    }
}

// ---------------------------------------------------------------------------
extern "C" void kernel_launch(void* const* d_in, const int* in_sizes, int n_in,
                              void* d_out, int out_size, void* d_ws, size_t ws_size,
                              hipStream_t stream) {
    const float* x      = (const float*)d_in[0];  // (64,78,128,80)
    const float* w_ih_t = (const float*)d_in[1];  // (256,80)
    const float* w_hh_t = (const float*)d_in[2];  // (256,64)
    const float* b_ih_t = (const float*)d_in[3];  // (256)
    const float* b_hh_t = (const float*)d_in[4];  // (256)
    const float* w_ih_n = (const float*)d_in[5];  // (8,64)
    const float* w_hh_n = (const float*)d_in[6];  // (8,2)
    const float* b_ih_n = (const float*)d_in[7];  // (8)
    const float* b_hh_n = (const float*)d_in[8];  // (8)
    float* out = (float*)d_out;                   // (64,128,156)

    if (ws_size >= GX_BYTES) {
        float* gx = (float*)d_ws;                 // [638976][256] = 654 MB
        gx_gemm<<<dim3(NROWS / GM, 256 / GN), 256, 0, stream>>>(
            x, w_ih_t, b_ih_t, b_hh_t, gx);
        rec_h3<<<NSEQ / (8 * SPW), 512, 0, stream>>>(gx, w_hh_t);
        note_scan2<<<NBT / 64, 64, 0, stream>>>(
            gx, w_ih_n, w_hh_n, b_ih_n, b_hh_n, out);
    } else {
        float* gxn = (float*)d_ws;                // 20.4 MB
        time_lstm_fused_fb<<<NSEQ / SB, 512, 0, stream>>>(
            x, w_ih_t, w_hh_t, b_ih_t, b_hh_t, w_ih_n, b_ih_n, b_hh_n, gxn);
        note_scan_kernel<<<NBT / 64, 64, 0, stream>>>(gxn, w_hh_n, out);
    }
}

// Round 7
// 1387.256 us; speedup vs baseline: 3.6057x; 3.6057x over previous
//
#include <hip/hip_runtime.h>
#include <math.h>

// Problem dims (fixed)
#define NOTES 78
#define IN_DIM 80
#define T_HID 64
#define N_HID 2
#define BATCH 64
#define TLEN 128
#define NSEQ (BATCH * NOTES)          // 4992 time-LSTM sequences
#define NBT  (BATCH * TLEN)           // 8192 note-LSTM sequences
#define SB   4                        // sequences per block in time-LSTM

__device__ __forceinline__ float sigf(float x) { return 1.0f / (1.0f + expf(-x)); }
__device__ __forceinline__ float rdl(float v, int k) {
    return __int_as_float(__builtin_amdgcn_readlane(__float_as_int(v), k));
}

// ---------------------------------------------------------------------------
// Fused time-LSTM + note-input projection.  R11 = R5 (measured 1160us) with
// ONE change: __launch_bounds__(512,4) -> (512,2).
//   R5 counters: VGPR_Count=64 but the x-waves need ~115 live regs (80 weight
//   + 35 working). The (512,4) bound implies a 128-reg cap; the allocator
//   split it 64 VGPR + ~64 AGPR (unified file) and pays v_accvgpr_read per
//   weight use -> measured 878us issue vs 449us useful (1.95x).
//   (512,2) raises the cap to 256 so the working set fits in arch VGPRs.
//   R10 lesson (rec_h3): allocator register-target failures turn into
//   catastrophic scratch traffic when combined with streaming loads; keep
//   the on-chip fused structure and fix the budget instead.
// ---------------------------------------------------------------------------
__global__ __launch_bounds__(512, 2)
void time_lstm_fused(const float* __restrict__ x,
                     const float* __restrict__ w_ih,
                     const float* __restrict__ w_hh,
                     const float* __restrict__ b_ih,
                     const float* __restrict__ b_hh,
                     const float* __restrict__ w_ih_n,
                     const float* __restrict__ b_ih_n,
                     const float* __restrict__ b_hh_n,
                     float* __restrict__ gxn) {
    __shared__ float hbuf[SB][T_HID];    // 1 KB
    __shared__ float Gx[2][SB][256];     // 8 KB  x-part partials (kh=0 incl bias)
    __shared__ float Gh[2][SB][256];     // 8 KB  h-part partials

    const int tid  = threadIdx.x;
    const int s0   = blockIdx.x * SB;
    const int wid  = tid >> 6;           // 0..3 = x-waves; 4..7 = h-waves
    const int lane = tid & 63;
    const bool isx = (wid < 4);
    const int lw   = isx ? wid : (wid - 4);
    const int kh   = lw >> 1;            // k-half index (0/1)
    const int gh   = lw & 1;             // gate-half index (0/1)
    const int g0   = (gh << 7) | (2 * lane);   // first of 2 owned gates

    // ---- weight registers: 2 gate rows x one k-half per thread ----
    float4 wA[10], wB[10];               // x: 10 f4 each; h: 8 f4 each
    float biasA = 0.0f, biasB = 0.0f;
    if (isx) {
        const float4* pA = (const float4*)(w_ih + (size_t)g0 * IN_DIM + 40 * kh);
        const float4* pB = (const float4*)(w_ih + (size_t)(g0 + 1) * IN_DIM + 40 * kh);
#pragma unroll
        for (int j = 0; j < 10; j++) { wA[j] = pA[j]; wB[j] = pB[j]; }
        if (kh == 0) {                   // bias counted exactly once
            biasA = b_ih[g0] + b_hh[g0];
            biasB = b_ih[g0 + 1] + b_hh[g0 + 1];
        }
    } else {
        const float4* pA = (const float4*)(w_hh + (size_t)g0 * T_HID + 32 * kh);
        const float4* pB = (const float4*)(w_hh + (size_t)(g0 + 1) * T_HID + 32 * kh);
#pragma unroll
        for (int j = 0; j < 8; j++) { wA[j] = pA[j]; wB[j] = pB[j]; }
    }

    // x row bases (uniform -> SGPR)
    const float* xr[SB];
#pragma unroll
    for (int s = 0; s < SB; s++) xr[s] = x + (size_t)(s0 + s) * TLEN * IN_DIM;

    // x load offset: lanes 0..39 hold the 40 k-values of this wave's half.
    // (clamp keeps t=127/kh=1 loads in-bounds; readlane only uses idx<=39)
    const int ol = 40 * kh + (lane < 39 ? lane : 39);

    float xa[SB], xna[SB];
    if (isx) {
#pragma unroll
        for (int s = 0; s < SB; s++) xa[s] = xr[s][ol];
    }

    // ---- h-wave identities: phase-B (seq=lw, unit=lane) + gxn projection ----
    float cst = 0.0f;
    const int hol = (kh << 5) | (lane & 31);   // LDS h operand, 2-way bcast (free)
    const int nj = (lane >> 3) & 7;
    const int nk = lane & 7;
    float wn[8];
    float nbias = 0.0f;
    float* gout = gxn;
    if (!isx) {
#pragma unroll
        for (int i = 0; i < 8; i++) wn[i] = w_ih_n[nj * 64 + nk * 8 + i];
        nbias = b_ih_n[nj] + b_hh_n[nj];
        const int sglb = s0 + lw;
        const int nb = sglb / NOTES, nn = sglb % NOTES;
        gout = gxn + ((size_t)nn * NBT + (size_t)nb * TLEN) * 8 + nj;
    }

    if (tid < SB * T_HID) hbuf[tid >> 6][tid & 63] = 0.0f;
    __syncthreads();

    for (int t = 0; t < TLEN; t++) {
        if (isx) {
            // prefetch x(t+1) into registers (latency hides under MAC loop)
            if (t + 1 < TLEN) {
#pragma unroll
                for (int s = 0; s < SB; s++) xna[s] = xr[s][(t + 1) * IN_DIM + ol];
            }
            // ---- phase A (x): 10 k4 x 4 seqs, 1 readlane feeds 2 fma ----
            float aA[SB], aB[SB];
#pragma unroll
            for (int s = 0; s < SB; s++) { aA[s] = biasA; aB[s] = biasB; }
#pragma unroll
            for (int k4 = 0; k4 < 10; k4++) {
                const float4 vA = wA[k4], vB = wB[k4];
#pragma unroll
                for (int s = 0; s < SB; s++) {
                    const float r0 = rdl(xa[s], 4 * k4 + 0);
                    const float r1 = rdl(xa[s], 4 * k4 + 1);
                    const float r2 = rdl(xa[s], 4 * k4 + 2);
                    const float r3 = rdl(xa[s], 4 * k4 + 3);
                    aA[s] = fmaf(vA.x, r0, aA[s]);  aB[s] = fmaf(vB.x, r0, aB[s]);
                    aA[s] = fmaf(vA.y, r1, aA[s]);  aB[s] = fmaf(vB.y, r1, aB[s]);
                    aA[s] = fmaf(vA.z, r2, aA[s]);  aB[s] = fmaf(vB.z, r2, aB[s]);
                    aA[s] = fmaf(vA.w, r3, aA[s]);  aB[s] = fmaf(vB.w, r3, aB[s]);
                }
            }
#pragma unroll
            for (int s = 0; s < SB; s++)
                *(float2*)&Gx[kh][s][g0] = make_float2(aA[s], aB[s]);
        } else {
            // ---- gxn for h_{t-1} ----
            if (t > 0) {
                float p = 0.0f;
#pragma unroll
                for (int i = 0; i < 8; i++) p = fmaf(wn[i], hbuf[lw][nk * 8 + i], p);
                p += __shfl_xor(p, 1);
                p += __shfl_xor(p, 2);
                p += __shfl_xor(p, 4);
                if (nk == 0) gout[(size_t)(t - 1) * 8] = p + nbias;
            }
            // ---- phase A (h): 8 k4 x 4 seqs ----
            float hv[SB];
#pragma unroll
            for (int s = 0; s < SB; s++) hv[s] = hbuf[s][hol];
            float aA[SB], aB[SB];
#pragma unroll
            for (int s = 0; s < SB; s++) { aA[s] = 0.0f; aB[s] = 0.0f; }
#pragma unroll
            for (int k4 = 0; k4 < 8; k4++) {
                const float4 vA = wA[k4], vB = wB[k4];
#pragma unroll
                for (int s = 0; s < SB; s++) {
                    const float r0 = rdl(hv[s], 4 * k4 + 0);
                    const float r1 = rdl(hv[s], 4 * k4 + 1);
                    const float r2 = rdl(hv[s], 4 * k4 + 2);
                    const float r3 = rdl(hv[s], 4 * k4 + 3);
                    aA[s] = fmaf(vA.x, r0, aA[s]);  aB[s] = fmaf(vB.x, r0, aB[s]);
                    aA[s] = fmaf(vA.y, r1, aA[s]);  aB[s] = fmaf(vB.y, r1, aB[s]);
                    aA[s] = fmaf(vA.z, r2, aA[s]);  aB[s] = fmaf(vB.z, r2, aB[s]);
                    aA[s] = fmaf(vA.w, r3, aA[s]);  aB[s] = fmaf(vB.w, r3, aB[s]);
                }
            }
#pragma unroll
            for (int s = 0; s < SB; s++)
                *(float2*)&Gh[kh][s][g0] = make_float2(aA[s], aB[s]);
        }
        __syncthreads();   // barrier 1: all 4 partial buffers complete

        if (!isx) {
            // ---- phase B: combine 4 partials, activate, update state ----
            const float i_p = Gx[0][lw][lane]       + Gx[1][lw][lane]
                            + Gh[0][lw][lane]       + Gh[1][lw][lane];
            const float f_p = Gx[0][lw][64 + lane]  + Gx[1][lw][64 + lane]
                            + Gh[0][lw][64 + lane]  + Gh[1][lw][64 + lane];
            const float g_p = Gx[0][lw][128 + lane] + Gx[1][lw][128 + lane]
                            + Gh[0][lw][128 + lane] + Gh[1][lw][128 + lane];
            const float o_p = Gx[0][lw][192 + lane] + Gx[1][lw][192 + lane]
                            + Gh[0][lw][192 + lane] + Gh[1][lw][192 + lane];
            cst = sigf(f_p) * cst + sigf(i_p) * tanhf(g_p);
            const float h = sigf(o_p) * tanhf(cst);
            hbuf[lw][lane] = h;
        } else if (t + 1 < TLEN) {
#pragma unroll
            for (int s = 0; s < SB; s++) xa[s] = xna[s];
        }
        __syncthreads();   // barrier 2: hbuf ready; partials free for reuse
    }

    // epilogue: gxn for h_127
    if (!isx) {
        float p = 0.0f;
#pragma unroll
        for (int i = 0; i < 8; i++) p = fmaf(wn[i], hbuf[lw][nk * 8 + i], p);
        p += __shfl_xor(p, 1);
        p += __shfl_xor(p, 2);
        p += __shfl_xor(p, 4);
        if (nk == 0) gout[(size_t)(TLEN - 1) * 8] = p + nbias;
    }
}

// ---------------------------------------------------------------------------
// Note-LSTM scan over 78 notes, fresh zero state per (b,t).
// One thread per bt. Output buffered 2 notes at a time with static
// indices (a runtime-indexed res[156] array was scratch-allocated).
// ---------------------------------------------------------------------------
__global__ __launch_bounds__(64)
void note_scan_kernel(const float* __restrict__ gxn,
                      const float* __restrict__ w_hh_n,
                      float* __restrict__ out) {
    const int bt = blockIdx.x * 64 + threadIdx.x;         // < 8192
    float wh[16];
#pragma unroll
    for (int i = 0; i < 16; i++) wh[i] = w_hh_n[i];       // [8][2] row-major
    float h0 = 0.f, h1 = 0.f, c0 = 0.f, c1 = 0.f;

    const float4* gp = (const float4*)gxn;                // f4 index = (n*NBT+bt)*2
    float4* op = (float4*)(out + (size_t)bt * (NOTES * N_HID));

    size_t idx = (size_t)bt * 2;
    float4 ga = gp[idx], gb = gp[idx + 1];
    for (int n0 = 0; n0 < NOTES; n0 += 2) {
        float r[4];
#pragma unroll
        for (int u = 0; u < 2; u++) {
            const int n = n0 + u;
            float4 na, nb2;
            if (n + 1 < NOTES) {
                const size_t nidx = ((size_t)(n + 1) * NBT + bt) * 2;
                na  = gp[nidx];
                nb2 = gp[nidx + 1];
            }
            const float i0 = ga.x + wh[0]  * h0 + wh[1]  * h1;
            const float i1 = ga.y + wh[2]  * h0 + wh[3]  * h1;
            const float f0 = ga.z + wh[4]  * h0 + wh[5]  * h1;
            const float f1 = ga.w + wh[6]  * h0 + wh[7]  * h1;
            const float g0 = gb.x + wh[8]  * h0 + wh[9]  * h1;
            const float g1 = gb.y + wh[10] * h0 + wh[11] * h1;
            const float o0 = gb.z + wh[12] * h0 + wh[13] * h1;
            const float o1 = gb.w + wh[14] * h0 + wh[15] * h1;
            c0 = sigf(f0) * c0 + sigf(i0) * tanhf(g0);
            c1 = sigf(f1) * c1 + sigf(i1) * tanhf(g1);
            h0 = sigf(o0) * tanhf(c0);
            h1 = sigf(o1) * tanhf(c1);
            r[2 * u + 0] = (h0 > 0.5f) ? 1.0f : 0.0f;
            r[2 * u + 1] = (h1 > 0.5f) ? 1.0f : 0.0f;
            ga = na; gb = nb2;
        }
        op[n0 >> 1] = make_float4(r[0], r[1], r[2], r[3]);
    }
}

// ---------------------------------------------------------------------------
extern "C" void kernel_launch(void* const* d_in, const int* in_sizes, int n_in,
                              void* d_out, int out_size, void* d_ws, size_t ws_size,
                              hipStream_t stream) {
    const float* x      = (const float*)d_in[0];  // (64,78,128,80)
    const float* w_ih_t = (const float*)d_in[1];  // (256,80)
    const float* w_hh_t = (const float*)d_in[2];  // (256,64)
    const float* b_ih_t = (const float*)d_in[3];  // (256)
    const float* b_hh_t = (const float*)d_in[4];  // (256)
    const float* w_ih_n = (const float*)d_in[5];  // (8,64)
    const float* w_hh_n = (const float*)d_in[6];  // (8,2)
    const float* b_ih_n = (const float*)d_in[7];  // (8)
    const float* b_hh_n = (const float*)d_in[8];  // (8)
    float* out = (float*)d_out;                   // (64,128,156)

    // workspace: gxn = [78][8192][8] fp32 = 20.4 MB
    float* gxn = (float*)d_ws;

    time_lstm_fused<<<NSEQ / SB, 512, 0, stream>>>(
        x, w_ih_t, w_hh_t, b_ih_t, b_hh_t, w_ih_n, b_ih_n, b_hh_n, gxn);
    note_scan_kernel<<<NBT / 64, 64, 0, stream>>>(gxn, w_hh_n, out);
}